// Round 8
// baseline (15167.488 us; speedup 1.0000x reference)
//
#include <hip/hip_runtime.h>
#include <hip/hip_fp16.h>
#include <math.h>

// Problem dims
#define B_  32
#define S_  256
#define I_  256
#define H_  512
#define N_  128
#define C_  64
#define O_  256
#define P_  268          // 4*C + 12
#define K_  832          // I + C + H  (x | r | h)
#define EPSX 1e-8f
#define MST  68          // LDS M row stride (16B-aligned, proven)

// Workspace layout (float offsets). Total 5,786,624 floats = 23.1 MB.
#define OFF_HH   0
#define SZ_HH    (B_*S_*H_)                 // h history [b][t][u]
#define OFF_RH   (OFF_HH + SZ_HH)
#define SZ_RH    (B_*S_*C_)                 // r history [b][t][c]
#define OFF_WOT  (OFF_RH + SZ_RH)
#define SZ_WOT   ((H_+C_)*O_)               // W_out transposed [k][o]
#define OFF_WHH  (OFF_WOT + SZ_WOT)
#define SZ_WHH_F ((P_*H_)/2)                // W_head fp16 (137216 halves)
#define OFF_WG   (OFF_WHH + SZ_WHH_F)
#define SZ_WG_H  (K_*H_*4)                  // gate weights fp16 [k][u][gate]

__device__ __forceinline__ float sigm(float x) { return 1.f / (1.f + expf(-x)); }
__device__ __forceinline__ float splus(float x) {
    return fmaxf(x, 0.f) + log1pf(expf(-fabsf(x)));
}
__device__ __forceinline__ float wave_max(float v) {
    #pragma unroll
    for (int s = 1; s < 64; s <<= 1) v = fmaxf(v, __shfl_xor(v, s, 64));
    return v;
}
__device__ __forceinline__ float wave_sum(float v) {
    #pragma unroll
    for (int s = 1; s < 64; s <<= 1) v += __shfl_xor(v, s, 64);
    return v;
}

// ---------------- prep: weight transposes / fp16 packs ---------------------
// WoT[k][o] = W_out[o][k]
// W_head -> fp16 (row-major, as before)
// Gate weights -> fp16 packed [k][u][gate]: one 8B load yields a unit's
// 4 gate weights for column k. k<320 -> W_ih columns (x|r); k>=320 -> W_hh.
__global__ __launch_bounds__(256)
void prep_kernel(const float* __restrict__ Wih, const float* __restrict__ Whh,
                 const float* __restrict__ Whead, const float* __restrict__ Wout,
                 float* __restrict__ ws)
{
    int g = blockIdx.x * 256 + threadIdx.x;
    if (g < SZ_WOT) {
        int o = g & 255, k = g >> 8;
        ws[OFF_WOT + g] = Wout[o * (H_ + C_) + k];
        return;
    }
    g -= SZ_WOT;
    if (g < P_ * H_) {
        ((__half*)(ws + OFF_WHH))[g] = __float2half(Whead[g]);
        return;
    }
    g -= P_ * H_;
    if (g < SZ_WG_H) {
        int k    = g >> 11;            // 0..831
        int rest = g & 2047;
        int u    = rest >> 2;          // 0..511
        int gate = rest & 3;           // 0..3 = i,f,g,o
        int row  = gate * H_ + u;
        float v = (k < I_ + C_) ? Wih[row * (I_ + C_) + k]
                                : Whh[row * H_ + (k - (I_ + C_))];
        ((__half*)(ws + OFF_WG))[g] = __float2half(v);
        return;
    }
}

// ---------------- per-batch NTM recurrence (ZERO inter-block sync) ---------
// 32 blocks x 1024 threads, one block per batch. Everything local:
//   gates GEMM: 2048x832 fp16-weight/fp32-acc, split-K over thread halves
//   LSTM activation -> h (a_lds + history)
//   head GEMM fp16 -> p_lds
//   addressing: wave0=read head, wave1=write head, fully in-register
//   M update in LDS; r via LDS + shuffle reduce
// No flags, no spin, no cooperative launch, no agent atomics.
__global__ __launch_bounds__(1024)
void ntm_batch(const float* __restrict__ x, const float* __restrict__ bl,
               const float* __restrict__ bhead, float* __restrict__ ws)
{
    __shared__ float Mlds[N_ * MST];     // 34816 B
    __shared__ float a_lds[K_];          // 3328 B: x[0..255] r[256..319] h[320..831]
    __shared__ float red[H_ * 4];        // 8192 B: split-K partials
    __shared__ float p_lds[272];
    __shared__ float wldsR[128];
    __shared__ float wldsW[128];

    const int tid  = threadIdx.x;
    const int b    = blockIdx.x;
    const int u    = tid & 511;          // unit
    const int half = tid >> 9;           // split-K half

    const float* xb = x + (size_t)b * (S_ * I_);
    float* hH = ws + OFF_HH + (size_t)b * (S_ * H_);
    float* rH = ws + OFF_RH + (size_t)b * (S_ * C_);
    const unsigned short* whG = (const unsigned short*)(ws + OFF_WG);
    const unsigned short* whH = (const unsigned short*)(ws + OFF_WHH);

    // ---- init ----
    for (int idx = tid; idx < N_ * C_; idx += 1024)
        Mlds[(idx >> 6) * MST + (idx & 63)] = 0.01f;
    if (tid < 256)            a_lds[tid] = xb[tid];          // x[0]
    else if (tid < K_)        a_lds[tid] = 0.f;              // r,h = 0
    if (tid < N_) {
        wldsR[tid] = (tid == 0) ? 1.f : 0.f;
        wldsW[tid] = (tid == 0) ? 1.f : 0.f;
    }
    float c_st = 0.f;
    float b_i = 0.f, b_f = 0.f, b_g = 0.f, b_o = 0.f;
    if (half == 0) {
        b_i = bl[u];          b_f = bl[H_ + u];
        b_g = bl[2*H_ + u];   b_o = bl[3*H_ + u];
    }
    __syncthreads();

    const int kbase = half * 416;

    for (int t = 0; t < S_; ++t) {
        // ---- gates GEMM: acc[gate] over this thread's K-half ----
        float a0 = 0.f, a1 = 0.f, a2 = 0.f, a3 = 0.f;
        {
            const unsigned short* wp = whG + ((size_t)kbase << 11) + (u << 2);
            #pragma unroll 4
            for (int i = 0; i < 416; ++i) {
                union { unsigned long long q; __half2 h2[2]; } w;
                w.q = *(const unsigned long long*)wp;
                const float av = a_lds[kbase + i];
                const float2 w01 = __half22float2(w.h2[0]);
                const float2 w23 = __half22float2(w.h2[1]);
                a0 = fmaf(w01.x, av, a0);
                a1 = fmaf(w01.y, av, a1);
                a2 = fmaf(w23.x, av, a2);
                a3 = fmaf(w23.y, av, a3);
                wp += 2048;
            }
        }
        if (half == 1) {
            float4 r4 = {a0, a1, a2, a3};
            *(float4*)&red[u * 4] = r4;
        }
        __syncthreads();                 // A: partials + a_lds reads done

        if (half == 0) {
            const float4 r4 = *(const float4*)&red[u * 4];
            const float gI = a0 + r4.x + b_i;
            const float gF = a1 + r4.y + b_f;
            const float gG = a2 + r4.z + b_g;
            const float gO = a3 + r4.w + b_o;
            const float cN = sigm(gF) * c_st + sigm(gI) * tanhf(gG);
            const float hN = sigm(gO) * tanhf(cN);
            c_st = cN;
            a_lds[320 + u] = hN;
            hH[(size_t)t * H_ + u] = hN;          // coalesced history
        } else if (t + 1 < S_ && tid >= 512 && tid < 768) {
            // prefetch x[t+1] (a_lds[0..255] free after barrier A)
            a_lds[tid - 512] = xb[(size_t)(t + 1) * I_ + (tid - 512)];
        }
        __syncthreads();                 // B: h + x ready

        // ---- head GEMM (fp16): p = W_head @ h + b_head, 2 thr/row ----
        if (tid < 2 * P_) {
            const int row = tid >> 1, sub = tid & 1;
            const unsigned short* wrow = whH + row * H_ + sub * 256;
            const float* hb = &a_lds[320 + sub * 256];
            float acch = 0.f;
            #pragma unroll 4
            for (int k2 = 0; k2 < 256; k2 += 8) {
                float4 raw = *(const float4*)&wrow[k2];   // 8 halves
                const __half2* hp = (const __half2*)&raw;
                float2 f0 = __half22float2(hp[0]);
                float2 f1 = __half22float2(hp[1]);
                float2 f2 = __half22float2(hp[2]);
                float2 f3 = __half22float2(hp[3]);
                acch += f0.x * hb[k2]     + f0.y * hb[k2 + 1]
                      + f1.x * hb[k2 + 2] + f1.y * hb[k2 + 3]
                      + f2.x * hb[k2 + 4] + f2.y * hb[k2 + 5]
                      + f3.x * hb[k2 + 6] + f3.y * hb[k2 + 7];
            }
            acch += __shfl_xor(acch, 1, 64);
            if (sub == 0) p_lds[row] = acch + bhead[row];
        }
        __syncthreads();                 // C: p ready

        // ---- addressing: wave0 = read head, wave1 = write head -----------
        // Fully in-register; lane l owns n0=l and n1=64+l. Zero barriers.
        {
            const int wv = tid >> 6, l = tid & 63;
            if (wv < 2) {
                const int o = wv ? 70 : 0;
                const float beta = splus(p_lds[o + 64]);
                const float gate = sigm(p_lds[o + 65]);
                const float sa = p_lds[o + 66], sbv = p_lds[o + 67],
                            sc = p_lds[o + 68];
                const float sm3 = fmaxf(sa, fmaxf(sbv, sc));
                const float ea = __expf(sa - sm3), eb = __expf(sbv - sm3),
                            ec = __expf(sc - sm3);
                const float es3 = ea + eb + ec;
                const float s0 = ea / es3, s1 = eb / es3, s2 = ec / es3;
                const float gamma = 1.f + splus(p_lds[o + 69]);
                float kk = 0.f;
                #pragma unroll 8
                for (int c = 0; c < C_; ++c) {
                    const float kv = p_lds[o + c]; kk += kv * kv;
                }
                const float knorm = sqrtf(kk) + EPSX;
                float dotA = 0.f, mmA = 0.f, dotB = 0.f, mmB = 0.f;
                #pragma unroll
                for (int c = 0; c < C_; c += 4) {
                    const float4 ma = *(const float4*)&Mlds[l * MST + c];
                    const float4 mb = *(const float4*)&Mlds[(64 + l) * MST + c];
                    const float k0 = p_lds[o + c],     k1 = p_lds[o + c + 1];
                    const float k2 = p_lds[o + c + 2], k3 = p_lds[o + c + 3];
                    dotA += ma.x*k0 + ma.y*k1 + ma.z*k2 + ma.w*k3;
                    mmA  += ma.x*ma.x + ma.y*ma.y + ma.z*ma.z + ma.w*ma.w;
                    dotB += mb.x*k0 + mb.y*k1 + mb.z*k2 + mb.w*k3;
                    mmB  += mb.x*mb.x + mb.y*mb.y + mb.z*mb.z + mb.w*mb.w;
                }
                const float zA = beta * (dotA / ((sqrtf(mmA) + EPSX) * knorm));
                const float zB = beta * (dotB / ((sqrtf(mmB) + EPSX) * knorm));
                const float zmax = wave_max(fmaxf(zA, zB));
                const float eA = __expf(zA - zmax), eB = __expf(zB - zmax);
                const float esum = wave_sum(eA + eB);
                const float wcA = eA / esum, wcB = eB / esum;
                const float wpvA = wv ? wldsW[l] : wldsR[l];
                const float wpvB = wv ? wldsW[64 + l] : wldsR[64 + l];
                const float wgA = gate * wcA + (1.f - gate) * wpvA;
                const float wgB = gate * wcB + (1.f - gate) * wpvB;
                // circular shift over n=0..127 split across two regs
                const float upA  = __shfl(wgA, (l + 1) & 63, 64);
                const float upB  = __shfl(wgB, (l + 1) & 63, 64);
                const float dnA  = __shfl(wgA, (l - 1) & 63, 64);
                const float dnB  = __shfl(wgB, (l - 1) & 63, 64);
                const float wgA0 = __shfl(wgA, 0, 64);
                const float wgB0 = __shfl(wgB, 0, 64);
                const float wgA63 = __shfl(wgA, 63, 64);
                const float wgB63 = __shfl(wgB, 63, 64);
                const float p1A = (l < 63) ? upA : wgB0;    // wg[n0+1]
                const float m1A = (l > 0)  ? dnA : wgB63;   // wg[n0-1] (wraps to 127)
                const float p1B = (l < 63) ? upB : wgA0;    // wg[n1+1] (wraps to 0)
                const float m1B = (l > 0)  ? dnB : wgA63;   // wg[n1-1]
                const float wsA = s0 * p1A + s1 * wgA + s2 * m1A;
                const float wsB = s0 * p1B + s1 * wgB + s2 * m1B;
                const float wpA = __powf(wsA + EPSX, gamma);
                const float wpB = __powf(wsB + EPSX, gamma);
                const float psum = wave_sum(wpA + wpB);
                const float wnA = wpA / psum, wnB = wpB / psum;
                if (wv) { wldsW[l] = wnA; wldsW[64 + l] = wnB; }
                else    { wldsR[l] = wnA; wldsR[64 + l] = wnB; }
            }
        }
        __syncthreads();                 // D: w_r, w_w ready

        // ---- M = M*(1 - w_w e) + w_w a  (LDS) ----
        #pragma unroll
        for (int rep = 0; rep < 2; ++rep) {
            const int idx = tid + rep * 1024;
            const int n = idx >> 4;
            const int c = (idx & 15) << 2;
            const float wwn = wldsW[n];
            float4 m4 = *(float4*)&Mlds[n * MST + c];
            m4.x = m4.x * (1.f - wwn * sigm(p_lds[140 + c]))     + wwn * p_lds[204 + c];
            m4.y = m4.y * (1.f - wwn * sigm(p_lds[140 + c + 1])) + wwn * p_lds[204 + c + 1];
            m4.z = m4.z * (1.f - wwn * sigm(p_lds[140 + c + 2])) + wwn * p_lds[204 + c + 2];
            m4.w = m4.w * (1.f - wwn * sigm(p_lds[140 + c + 3])) + wwn * p_lds[204 + c + 3];
            *(float4*)&Mlds[n * MST + c] = m4;
        }
        __syncthreads();                 // E: M ready

        // ---- r = w_r @ M_new -> a_lds + history ----
        if (tid < 512) {
            const int c = tid >> 3, ns = tid & 7;
            float accr = 0.f;
            #pragma unroll
            for (int i = 0; i < 16; ++i) {
                const int n = ns + 8 * i;
                accr += wldsR[n] * Mlds[n * MST + c];
            }
            accr += __shfl_xor(accr, 4, 64);
            accr += __shfl_xor(accr, 2, 64);
            accr += __shfl_xor(accr, 1, 64);
            if (ns == 0) {
                a_lds[256 + c] = accr;
                rH[(size_t)t * C_ + c] = accr;
            }
        }
        __syncthreads();                 // F: r ready for next gates GEMM
    }
}

// ---------------- final output GEMM ----------------
__global__ __launch_bounds__(256)
void out_kernel(const float* __restrict__ ws, const float* __restrict__ bout,
                float* __restrict__ out)
{
    __shared__ float actL[(H_ + C_) * 16];   // 36,864 B
    const float* WoT = ws + OFF_WOT;
    const int t   = blockIdx.x >> 1;
    const int bh  = blockIdx.x & 1;
    const int tid = threadIdx.x;

    for (int bl2 = 0; bl2 < 16; ++bl2) {
        const int b = bh * 16 + bl2;
        const float* hsrc = ws + OFF_HH + ((size_t)b * S_ + t) * H_;
        const float* rsrc = ws + OFF_RH + ((size_t)b * S_ + t) * C_;
        for (int k = tid; k < H_ + C_; k += 256) {
            const float v = (k < H_) ? hsrc[k] : rsrc[k - H_];
            actL[k * 16 + bl2] = v;
        }
    }
    __syncthreads();

    const int ot = tid & 63, bt = tid >> 6;
    const int o0 = ot * 4, bl0 = bt * 4;
    float acc[4][4] = {{0,0,0,0},{0,0,0,0},{0,0,0,0},{0,0,0,0}};
    for (int k = 0; k < H_ + C_; ++k) {
        const float4 w4 = *(const float4*)&WoT[k * O_ + o0];
        const float4 a4 = *(const float4*)&actL[k * 16 + bl0];
        const float wv[4] = {w4.x, w4.y, w4.z, w4.w};
        const float av[4] = {a4.x, a4.y, a4.z, a4.w};
        #pragma unroll
        for (int j = 0; j < 4; ++j)
            #pragma unroll
            for (int bb = 0; bb < 4; ++bb)
                acc[j][bb] += wv[j] * av[bb];
    }
    const float4 bo = *(const float4*)&bout[o0];
    #pragma unroll
    for (int bb = 0; bb < 4; ++bb) {
        const int b = bh * 16 + bl0 + bb;
        float4 res;
        res.x = acc[0][bb] + bo.x;
        res.y = acc[1][bb] + bo.y;
        res.z = acc[2][bb] + bo.z;
        res.w = acc[3][bb] + bo.w;
        *(float4*)&out[((size_t)b * S_ + t) * O_ + o0] = res;
    }
}

extern "C" void kernel_launch(void* const* d_in, const int* in_sizes, int n_in,
                              void* d_out, int out_size, void* d_ws, size_t ws_size,
                              hipStream_t stream)
{
    const float* x    = (const float*)d_in[0];
    const float* Wih  = (const float*)d_in[1];
    const float* Whh  = (const float*)d_in[2];
    const float* bl   = (const float*)d_in[3];
    const float* Whd  = (const float*)d_in[4];
    const float* bhd  = (const float*)d_in[5];
    const float* Wout = (const float*)d_in[6];
    const float* bout = (const float*)d_in[7];
    float* ws  = (float*)d_ws;    // needs 23.1 MB
    float* out = (float*)d_out;

    const int prep_total = SZ_WOT + P_ * H_ + SZ_WG_H;
    prep_kernel<<<(prep_total + 255) / 256, 256, 0, stream>>>(Wih, Whh, Whd, Wout, ws);

    ntm_batch<<<32, 1024, 0, stream>>>(x, bl, bhd, ws);

    out_kernel<<<512, 256, 0, stream>>>(ws, bout, out);
}

// Round 9
// 11881.934 us; speedup vs baseline: 1.2765x; 1.2765x over previous
//
#include <hip/hip_runtime.h>
#include <hip/hip_fp16.h>
#include <math.h>

// Problem dims
#define B_  32
#define S_  256
#define I_  256
#define H_  512
#define N_  128
#define C_  64
#define O_  256
#define P_  268          // 4*C + 12
#define K_  832          // I + C + H
#define HB  (H_*B_)      // 16384
#define EPSX 1e-8f

// Workspace layout (float offsets) — identical to baseline (29.4 MB, proven fit).
#define OFF_XT   0
#define SZ_XT    (S_*I_*B_)                 // x transposed [t][k][b]
#define OFF_HA   (OFF_XT + SZ_XT)
#define SZ_HA    ((S_+1)*H_*B_)             // h history [t][u][b]
#define OFF_RA   (OFF_HA + SZ_HA)
#define SZ_RA    ((S_+1)*C_*B_)             // r history [t][c][b]
#define OFF_CT   (OFF_RA + SZ_RA)
#define SZ_CT    (H_*B_)                    // LSTM c state [u][b]
#define OFF_M    (OFF_CT + SZ_CT)
#define SZ_M     (B_*N_*C_)                 // memory [b][n][c]
#define OFF_WR   (OFF_M + SZ_M)
#define SZ_W     (B_*N_)                    // w_r state [b][n]
#define OFF_WW   (OFF_WR + SZ_W)            // w_w state [b][n]
#define OFF_BAR  (OFF_WW + SZ_W)
#define SZ_BAR   8192                       // (unused in graph design)
#define OFF_WOT  (OFF_BAR + SZ_BAR)
#define SZ_WOT   ((H_+C_)*O_)               // W_out transposed [k][o]
#define OFF_WHH  (OFF_WOT + SZ_WOT)
#define SZ_WHH   ((P_*H_)/2)                // W_head fp16

__device__ __forceinline__ float sigm(float x) { return 1.f / (1.f + expf(-x)); }
__device__ __forceinline__ float splus(float x) {
    return fmaxf(x, 0.f) + log1pf(expf(-fabsf(x)));
}
__device__ __forceinline__ float wave_max(float v) {
    #pragma unroll
    for (int s = 1; s < 64; s <<= 1) v = fmaxf(v, __shfl_xor(v, s, 64));
    return v;
}
__device__ __forceinline__ float wave_sum(float v) {
    #pragma unroll
    for (int s = 1; s < 64; s <<= 1) v += __shfl_xor(v, s, 64);
    return v;
}

// ---------------- prep: transpose x & W_out, fp16 W_head, init state -------
__global__ __launch_bounds__(256)
void prep_kernel(const float* __restrict__ x, const float* __restrict__ Wout,
                 const float* __restrict__ Whead, float* __restrict__ ws)
{
    int g = blockIdx.x * 256 + threadIdx.x;
    if (g < SZ_XT) {                       // xT[t][k][b] = x[b][t][k]
        int b = g & 31, k = (g >> 5) & 255, t = g >> 13;
        ws[OFF_XT + g] = x[b * (S_*I_) + t * I_ + k];
        return;
    }
    g -= SZ_XT;
    if (g < SZ_WOT) {                      // WoT[k][o] = W_out[o][k]
        int o = g & 255, k = g >> 8;
        ws[OFF_WOT + g] = Wout[o * (H_ + C_) + k];
        return;
    }
    g -= SZ_WOT;
    if (g < HB)      { ws[OFF_HA + g] = 0.f;   return; }   // h slot 0
    g -= HB;
    if (g < C_*B_)   { ws[OFF_RA + g] = 0.f;   return; }   // r slot 0
    g -= C_*B_;
    if (g < SZ_CT)   { ws[OFF_CT + g] = 0.f;   return; }   // c state
    g -= SZ_CT;
    if (g < SZ_M)    { ws[OFF_M  + g] = 0.01f; return; }   // M
    g -= SZ_M;
    if (g < 2*SZ_W) {                      // w_r / w_w = e0 per batch
        ws[OFF_WR + g] = ((g & 127) == 0) ? 1.f : 0.f;
        return;
    }
    g -= 2*SZ_W;
    if (g < SZ_BAR)  { ws[OFF_BAR + g] = 0.f;  return; }
    g -= SZ_BAR;
    if (g < P_ * H_) {                     // W_head -> fp16
        ((__half*)(ws + OFF_WHH))[g] = __float2half(Whead[g]);
        return;
    }
}

// GEMM inner step: one k-column, 4 gate rows x 8 batches into acc.
#define GEMM_STEP(khat, ap) {                                             \
    const float4 a0 = *(const float4*)(ap);                               \
    const float4 a1 = *(const float4*)((ap) + 4);                         \
    const float2 w01 = *(const float2*)&Wt[(khat) * 18 + (rg << 2)];      \
    const float2 w23 = *(const float2*)&Wt[(khat) * 18 + (rg << 2) + 2];  \
    const float wv[4] = {w01.x, w01.y, w23.x, w23.y};                     \
    const float av[8] = {a0.x, a0.y, a0.z, a0.w, a1.x, a1.y, a1.z, a1.w}; \
    _Pragma("unroll")                                                     \
    for (int j = 0; j < 4; ++j)                                           \
        _Pragma("unroll")                                                 \
        for (int bb = 0; bb < 8; ++bb)                                    \
            acc[j][bb] += wv[j] * av[bb]; }

// ---------------- per-step kernel 1: gates GEMM + LSTM ---------------------
// 128 blocks x 512 threads. Block bi owns units [4bi, 4bi+4) for ALL 32
// batches. Stream ordering (graph) provides r[t]/h[t] visibility — no
// atomics, no flags. Weight slice (53 KB) staged from L2 each launch.
__global__ __launch_bounds__(512)
void gates_kernel(const float* __restrict__ Wih, const float* __restrict__ Whh,
                  const float* __restrict__ bl, float* __restrict__ ws, int t)
{
    __shared__ float Wt[K_ * 18];     // 59,904 B

    const float* xT = ws + OFF_XT;
    float* hA = ws + OFF_HA;
    const float* rA = ws + OFF_RA;
    float* cA = ws + OFF_CT;

    const int tid = threadIdx.x;
    const int bi  = blockIdx.x;

    // stage weight slice: float4 over k, 16 rows (4 units x 4 gates)
    for (int idx = tid; idx < 16 * 208; idx += 512) {
        const int rl = idx & 15, q = idx >> 4;
        const int k  = q << 2;
        const int row = (rl & 3) * H_ + bi * 4 + (rl >> 2);
        float4 w4;
        if (k < I_ + C_) w4 = *(const float4*)&Wih[row * (I_ + C_) + k];
        else             w4 = *(const float4*)&Whh[row * H_ + (k - (I_ + C_))];
        Wt[(k + 0) * 18 + rl] = w4.x;
        Wt[(k + 1) * 18 + rl] = w4.y;
        Wt[(k + 2) * 18 + rl] = w4.z;
        Wt[(k + 3) * 18 + rl] = w4.w;
    }
    __syncthreads();

    const int pair = tid >> 5;        // 0..15
    const int ks   = tid & 31;        // split-K lane
    const int rg   = pair >> 2;       // unit_local 0..3
    const int bg   = pair & 3;        // batch octet 0..3
    const int b0   = bg * 8;

    float acc[4][8];
    #pragma unroll
    for (int j = 0; j < 4; ++j)
        #pragma unroll
        for (int bb = 0; bb < 8; ++bb) acc[j][bb] = 0.f;

    const float* xs = xT + (size_t)t * I_ * B_;
    const float* rs = rA + (size_t)t * C_ * B_;
    const float* hs = hA + (size_t)t * HB;
    #pragma unroll
    for (int i = 0; i < 26; ++i) {
        const int k = ks + (i << 5);
        const float* ap;
        if (i < 8)       ap = xs + k * B_ + b0;
        else if (i < 10) ap = rs + (k - I_) * B_ + b0;
        else             ap = hs + (k - I_ - C_) * B_ + b0;
        GEMM_STEP(k, ap);
    }
    #pragma unroll
    for (int j = 0; j < 4; ++j)
        #pragma unroll
        for (int bb = 0; bb < 8; ++bb) {
            float v = acc[j][bb];
            v += __shfl_xor(v, 16, 64);
            v += __shfl_xor(v, 8, 64);
            v += __shfl_xor(v, 4, 64);
            v += __shfl_xor(v, 2, 64);
            v += __shfl_xor(v, 1, 64);
            acc[j][bb] = v;
        }
    if (ks == 0) {
        const int unit = bi * 4 + rg;
        const float bI = bl[unit];
        const float bF = bl[H_ + unit];
        const float bG = bl[2 * H_ + unit];
        const float bO = bl[3 * H_ + unit];
        float4 c0 = *(const float4*)&cA[unit * B_ + b0];
        float4 c1 = *(const float4*)&cA[unit * B_ + b0 + 4];
        float cin[8] = {c0.x, c0.y, c0.z, c0.w, c1.x, c1.y, c1.z, c1.w};
        float hv[8], cv[8];
        #pragma unroll
        for (int bb = 0; bb < 8; ++bb) {
            const float gI = acc[0][bb] + bI;
            const float gF = acc[1][bb] + bF;
            const float gG = acc[2][bb] + bG;
            const float gO = acc[3][bb] + bO;
            const float cN = sigm(gF) * cin[bb] + sigm(gI) * tanhf(gG);
            hv[bb] = sigm(gO) * tanhf(cN);
            cv[bb] = cN;
        }
        float4 h0 = {hv[0], hv[1], hv[2], hv[3]};
        float4 h1 = {hv[4], hv[5], hv[6], hv[7]};
        float* hd = &hA[(size_t)(t + 1) * HB + unit * B_ + b0];
        *(float4*)hd = h0;
        *(float4*)(hd + 4) = h1;
        float4 cw0 = {cv[0], cv[1], cv[2], cv[3]};
        float4 cw1 = {cv[4], cv[5], cv[6], cv[7]};
        *(float4*)&cA[unit * B_ + b0] = cw0;
        *(float4*)&cA[unit * B_ + b0 + 4] = cw1;
    }
}

// ---------------- per-step kernel 2: head + addressing + write + read ------
// 32 blocks x 512 threads, block b = batch b. State (M, w_r, w_w) in global.
__global__ __launch_bounds__(512)
void pb_kernel(const float* __restrict__ bhead, float* __restrict__ ws, int t)
{
    __shared__ float p_lds[P_];
    __shared__ float wldsR[128];
    __shared__ float wldsW[128];
    __shared__ float h_lds[H_];       // h staging; aliased scratch later

    const float* hA = ws + OFF_HA;
    float* rA  = ws + OFF_RA;
    float* Mem = ws + OFF_M;
    float* wR  = ws + OFF_WR;
    float* wW  = ws + OFF_WW;
    const unsigned short* whH = (const unsigned short*)(ws + OFF_WHH);

    const int tid = threadIdx.x;
    const int b   = blockIdx.x;
    float* Mb = Mem + (size_t)b * N_ * C_;

    const float* hs = hA + (size_t)(t + 1) * HB;
    h_lds[tid] = hs[tid * B_ + b];
    if (tid < 128)      wldsR[tid] = wR[b * 128 + tid];
    else if (tid < 256) wldsW[tid - 128] = wW[b * 128 + (tid - 128)];
    __syncthreads();

    // head GEMM (fp16 weights): p = W_head @ h + b_head, 2 thr/row
    {
        const int sub  = tid & 1;
        const int row0 = tid >> 1;
        const float* hb = &h_lds[sub * 256];
        #pragma unroll
        for (int rep = 0; rep < 2; ++rep) {
            const int row = (rep == 0) ? row0
                          : ((row0 < P_ - 256) ? row0 + 256 : -1);
            if (row >= 0) {
                const unsigned short* wrow = whH + row * H_ + sub * 256;
                float acch = 0.f;
                #pragma unroll 4
                for (int k2 = 0; k2 < 256; k2 += 8) {
                    float4 raw = *(const float4*)&wrow[k2];
                    const __half2* hp = (const __half2*)&raw;
                    float2 f0 = __half22float2(hp[0]);
                    float2 f1 = __half22float2(hp[1]);
                    float2 f2 = __half22float2(hp[2]);
                    float2 f3 = __half22float2(hp[3]);
                    acch += f0.x * hb[k2]     + f0.y * hb[k2 + 1]
                          + f1.x * hb[k2 + 2] + f1.y * hb[k2 + 3]
                          + f2.x * hb[k2 + 4] + f2.y * hb[k2 + 5]
                          + f3.x * hb[k2 + 6] + f3.y * hb[k2 + 7];
                }
                acch += __shfl_xor(acch, 1, 64);
                if (sub == 0) p_lds[row] = acch + bhead[row];
            }
        }
    }
    __syncthreads();

    // dual-pass addressing: grp0=read head, grp1=write head (concurrent)
    {
        float* wtmpA = h_lds;            // alias (h_lds dead)
        float* sbufA = h_lds + 256;
        const int grp = (tid >> 7) & 1;
        const int l   = tid & 127;
        const bool act256 = (tid < 256);
        const int o = grp ? 70 : 0;
        const int widx = (tid >> 6) & 1;

        float z = 0.f, gate = 0.f, s0 = 0.f, s1 = 0.f, s2 = 0.f,
              gamma = 1.f;
        if (act256) {
            float beta = splus(p_lds[o + 64]);
            gate = sigm(p_lds[o + 65]);
            float sa = p_lds[o + 66], sbv = p_lds[o + 67], sc = p_lds[o + 68];
            float sm3 = fmaxf(sa, fmaxf(sbv, sc));
            float ea = __expf(sa - sm3), eb = __expf(sbv - sm3),
                  ec = __expf(sc - sm3);
            float es3 = ea + eb + ec;
            s0 = ea / es3; s1 = eb / es3; s2 = ec / es3;
            gamma = 1.f + splus(p_lds[o + 69]);
            float kk = 0.f;
            #pragma unroll 8
            for (int c = 0; c < C_; ++c) {
                float kv = p_lds[o + c]; kk += kv * kv;
            }
            const float knorm = sqrtf(kk) + EPSX;
            float dot = 0.f, mm = 0.f;
            #pragma unroll
            for (int c = 0; c < C_; c += 4) {
                float4 m4 = *(const float4*)&Mb[l * C_ + c];
                dot += m4.x * p_lds[o + c]     + m4.y * p_lds[o + c + 1]
                     + m4.z * p_lds[o + c + 2] + m4.w * p_lds[o + c + 3];
                mm  += m4.x * m4.x + m4.y * m4.y + m4.z * m4.z + m4.w * m4.w;
            }
            z = beta * (dot / ((sqrtf(mm) + EPSX) * knorm));
        }
        float zm = wave_max(z);
        if (act256 && (tid & 63) == 0) sbufA[grp * 8 + widx] = zm;
        __syncthreads();
        const float zmax = fmaxf(sbufA[grp * 8], sbufA[grp * 8 + 1]);
        float ev = act256 ? __expf(z - zmax) : 0.f;
        float es = wave_sum(ev);
        if (act256 && (tid & 63) == 0) sbufA[grp * 8 + 2 + widx] = es;
        __syncthreads();
        const float esum = sbufA[grp * 8 + 2] + sbufA[grp * 8 + 3];
        if (act256) {
            float wc = ev / esum;
            float wprev = grp ? wldsW[l] : wldsR[l];
            wtmpA[grp * 128 + l] = gate * wc + (1.f - gate) * wprev;
        }
        __syncthreads();
        float wp = 0.f;
        if (act256) {
            float wsft = s0 * wtmpA[grp * 128 + ((l + 1) & 127)]
                       + s1 * wtmpA[grp * 128 + l]
                       + s2 * wtmpA[grp * 128 + ((l - 1) & 127)];
            wp = __powf(wsft + EPSX, gamma);
        }
        float ps = wave_sum(wp);
        if (act256 && (tid & 63) == 0) sbufA[grp * 8 + 4 + widx] = ps;
        __syncthreads();
        const float psum = sbufA[grp * 8 + 4] + sbufA[grp * 8 + 5];
        if (act256) {
            float wn = wp / psum;
            if (grp) wldsW[l] = wn; else wldsR[l] = wn;
        }
        __syncthreads();
    }

    // M = M*(1 - w_w e) + w_w a
    for (int idx = tid; idx < (N_ * C_) / 4; idx += 512) {
        const int n = idx >> 4;
        const int c = (idx & 15) << 2;
        const float wwn = wldsW[n];
        float4 m4 = *(float4*)&Mb[n * C_ + c];
        m4.x = m4.x * (1.f - wwn * sigm(p_lds[140 + c]))     + wwn * p_lds[204 + c];
        m4.y = m4.y * (1.f - wwn * sigm(p_lds[140 + c + 1])) + wwn * p_lds[204 + c + 1];
        m4.z = m4.z * (1.f - wwn * sigm(p_lds[140 + c + 2])) + wwn * p_lds[204 + c + 2];
        m4.w = m4.w * (1.f - wwn * sigm(p_lds[140 + c + 3])) + wwn * p_lds[204 + c + 3];
        *(float4*)&Mb[n * C_ + c] = m4;
    }
    __syncthreads();

    // r = w_r @ M_new -> publish; persist w_r/w_w
    {
        const int c = tid >> 3, ns = tid & 7;
        float accr = 0.f;
        #pragma unroll
        for (int i = 0; i < 16; ++i) {
            const int n = ns + 8 * i;
            accr += wldsR[n] * Mb[n * C_ + c];
        }
        accr += __shfl_xor(accr, 4, 64);
        accr += __shfl_xor(accr, 2, 64);
        accr += __shfl_xor(accr, 1, 64);
        if (ns == 0)
            rA[(size_t)(t + 1) * C_ * B_ + c * B_ + b] = accr;
    }
    if (tid < 128)      wR[b * 128 + tid] = wldsR[tid];
    else if (tid < 256) wW[b * 128 + (tid - 128)] = wldsW[tid - 128];
}

// ---------------- final output GEMM ----------------
__global__ __launch_bounds__(256)
void out_kernel(const float* __restrict__ ws, const float* __restrict__ bout,
                float* __restrict__ out)
{
    __shared__ float actL[(H_ + C_) * 16];
    const float* hA  = ws + OFF_HA;
    const float* rA  = ws + OFF_RA;
    const float* WoT = ws + OFF_WOT;
    const int t   = blockIdx.x >> 1;
    const int bh  = blockIdx.x & 1;
    const int tid = threadIdx.x;

    for (int idx = tid; idx < (H_ + C_) * 16; idx += 256) {
        const int k = idx >> 4, bl2 = idx & 15, b = bh * 16 + bl2;
        float v = (k < H_) ? hA[(size_t)(t + 1) * HB + k * B_ + b]
                           : rA[(size_t)(t + 1) * C_ * B_ + (k - H_) * B_ + b];
        actL[k * 16 + bl2] = v;
    }
    __syncthreads();

    const int ot = tid & 63, bt = tid >> 6;
    const int o0 = ot * 4, bl0 = bt * 4;
    float acc[4][4] = {{0,0,0,0},{0,0,0,0},{0,0,0,0},{0,0,0,0}};
    for (int k = 0; k < H_ + C_; ++k) {
        const float4 w4 = *(const float4*)&WoT[k * O_ + o0];
        const float4 a4 = *(const float4*)&actL[k * 16 + bl0];
        const float wv[4] = {w4.x, w4.y, w4.z, w4.w};
        const float av[4] = {a4.x, a4.y, a4.z, a4.w};
        #pragma unroll
        for (int j = 0; j < 4; ++j)
            #pragma unroll
            for (int bb = 0; bb < 4; ++bb)
                acc[j][bb] += wv[j] * av[bb];
    }
    const float4 bo = *(const float4*)&bout[o0];
    #pragma unroll
    for (int bb = 0; bb < 4; ++bb) {
        const int b = bh * 16 + bl0 + bb;
        float4 res;
        res.x = acc[0][bb] + bo.x;
        res.y = acc[1][bb] + bo.y;
        res.z = acc[2][bb] + bo.z;
        res.w = acc[3][bb] + bo.w;
        *(float4*)&out[((size_t)b * S_ + t) * O_ + o0] = res;
    }
}

extern "C" void kernel_launch(void* const* d_in, const int* in_sizes, int n_in,
                              void* d_out, int out_size, void* d_ws, size_t ws_size,
                              hipStream_t stream)
{
    const float* x    = (const float*)d_in[0];
    const float* Wih  = (const float*)d_in[1];
    const float* Whh  = (const float*)d_in[2];
    const float* bl   = (const float*)d_in[3];
    const float* Whd  = (const float*)d_in[4];
    const float* bhd  = (const float*)d_in[5];
    const float* Wout = (const float*)d_in[6];
    const float* bout = (const float*)d_in[7];
    float* ws  = (float*)d_ws;    // 29.4 MB (baseline layout)
    float* out = (float*)d_out;

    prep_kernel<<<10529, 256, 0, stream>>>(x, Wout, Whd, ws);

    for (int t = 0; t < S_; ++t) {
        gates_kernel<<<128, 512, 0, stream>>>(Wih, Whh, bl, ws, t);
        pb_kernel<<<32, 512, 0, stream>>>(bhd, ws, t);
    }

    out_kernel<<<512, 256, 0, stream>>>(ws, bout, out);
}

// Round 12
// 6575.774 us; speedup vs baseline: 2.3066x; 1.8069x over previous
//
#include <hip/hip_runtime.h>
#include <hip/hip_fp16.h>
#include <math.h>

// Problem dims
#define B_  32
#define S_  256
#define I_  256
#define H_  512
#define N_  128
#define C_  64
#define O_  256
#define P_  268          // 4*C + 12
#define K_  832          // I + C + H
#define HB  (H_*B_)      // 16384
#define EPSX 1e-8f
#define NBLK 160         // 32 PB blocks + 128 gate blocks
#define NPB  32
#define NGATE 128
#define MST  68          // LDS M row stride

// Workspace layout (float offsets) — unchanged from baseline.
#define OFF_XT   0
#define SZ_XT    (S_*I_*B_)
#define OFF_HA   (OFF_XT + SZ_XT)
#define SZ_HA    ((S_+1)*H_*B_)
#define OFF_RA   (OFF_HA + SZ_HA)
#define SZ_RA    ((S_+1)*C_*B_)
#define OFF_CT   (OFF_RA + SZ_RA)
#define SZ_CT    (H_*B_)
#define OFF_M    (OFF_CT + SZ_CT)
#define SZ_M     (B_*N_*C_)
#define OFF_WR   (OFF_M + SZ_M)
#define SZ_W     (B_*N_)
#define OFF_WW   (OFF_WR + SZ_W)
#define OFF_BAR  (OFF_WW + SZ_W)
#define SZ_BAR   8192                       // flag_h[128] @ +0, flag_r[32] @ +4096 (stride 16)
#define OFF_WOT  (OFF_BAR + SZ_BAR)
#define SZ_WOT   ((H_+C_)*O_)
#define OFF_WHH  (OFF_WOT + SZ_WOT)
#define SZ_WHH   ((P_*H_)/2)

__device__ __forceinline__ float sigm(float x) { return 1.f / (1.f + expf(-x)); }
__device__ __forceinline__ float splus(float x) {
    return fmaxf(x, 0.f) + log1pf(expf(-fabsf(x)));
}
__device__ __forceinline__ float wave_max(float v) {
    #pragma unroll
    for (int s = 1; s < 64; s <<= 1) v = fmaxf(v, __shfl_xor(v, s, 64));
    return v;
}
__device__ __forceinline__ float wave_sum(float v) {
    #pragma unroll
    for (int s = 1; s < 64; s <<= 1) v += __shfl_xor(v, s, 64);
    return v;
}

// ---- point-to-point flag wait — ALL-SLEEP (R11 A/B on power-throttle) -----
// Ledger: sync topology (R2-R4), poll traffic (R7), publish layout (R7) all
// neutral; the only lever that ever moved time was spin ACTIVITY (R5 heavy
// spin worse, R6 sleep-bystanders better). Surviving theory: chip is
// power-capped; junk-FMA polling depresses clocks chip-wide, inflating the
// compute phases. Endpoint of that axis: ZERO junk-FMA. One wave polls
// (2 flags/lane, s_sleep(1) between polls — same cadence, no FMA burn);
// waves 1..7 s_sleep(4) on the LDS mirror.
__device__ __forceinline__ void wait_flags(unsigned* flags, int nf, unsigned tgt,
                                           volatile unsigned* ldsp, int tid)
{
    const int wv = tid >> 6, ln = tid & 63;
    if (wv == 0) {
        const int i0 = (ln < nf) ? ln : nf - 1;
        const int i1 = (64 + ln < nf) ? 64 + ln : nf - 1;
        unsigned* p0 = &flags[i0 * 16];
        unsigned* p1 = &flags[i1 * 16];
        for (;;) {
            unsigned v0 = __hip_atomic_load(p0, __ATOMIC_RELAXED,
                                            __HIP_MEMORY_SCOPE_AGENT);
            unsigned v1 = __hip_atomic_load(p1, __ATOMIC_RELAXED,
                                            __HIP_MEMORY_SCOPE_AGENT);
            if (__all((int)((v0 >= tgt) && (v1 >= tgt)))) break;
            __builtin_amdgcn_s_sleep(1);
        }
        if (ln == 0) *ldsp = tgt;
    } else {
        while (*ldsp < tgt) __builtin_amdgcn_s_sleep(4);
    }
    __syncthreads();
}

// ---------------- prep: transpose x & W_out, fp16 W_head, init state -------
__global__ __launch_bounds__(256)
void prep_kernel(const float* __restrict__ x, const float* __restrict__ Wout,
                 const float* __restrict__ Whead, float* __restrict__ ws)
{
    int g = blockIdx.x * 256 + threadIdx.x;
    if (g < SZ_XT) {
        int b = g & 31, k = (g >> 5) & 255, t = g >> 13;
        ws[OFF_XT + g] = x[b * (S_*I_) + t * I_ + k];
        return;
    }
    g -= SZ_XT;
    if (g < SZ_WOT) {
        int o = g & 255, k = g >> 8;
        ws[OFF_WOT + g] = Wout[o * (H_ + C_) + k];
        return;
    }
    g -= SZ_WOT;
    if (g < HB)      { ws[OFF_HA + g] = 0.f;   return; }
    g -= HB;
    if (g < C_*B_)   { ws[OFF_RA + g] = 0.f;   return; }
    g -= C_*B_;
    if (g < SZ_CT)   { ws[OFF_CT + g] = 0.f;   return; }
    g -= SZ_CT;
    if (g < SZ_M)    { ws[OFF_M  + g] = 0.01f; return; }   // (unused: M in LDS)
    g -= SZ_M;
    if (g < 2*SZ_W)  { ws[OFF_WR + g] = 0.f;   return; }
    g -= 2*SZ_W;
    if (g < SZ_BAR)  { ws[OFF_BAR + g] = 0.f;  return; }
    g -= SZ_BAR;
    if (g < P_ * H_) {
        ((__half*)(ws + OFF_WHH))[g] = __float2half(Whead[g]);
        return;
    }
}

// GEMM inner step: one k-column, 4 gate rows x 8 batches into acc.
#define GEMM_STEP(khat, ap) {                                             \
    const float4 a0 = *(const float4*)(ap);                               \
    const float4 a1 = *(const float4*)((ap) + 4);                         \
    const float2 w01 = *(const float2*)&Wt[(khat) * 18 + (rg << 2)];      \
    const float2 w23 = *(const float2*)&Wt[(khat) * 18 + (rg << 2) + 2];  \
    const float wv[4] = {w01.x, w01.y, w23.x, w23.y};                     \
    const float av[8] = {a0.x, a0.y, a0.z, a0.w, a1.x, a1.y, a1.z, a1.w}; \
    _Pragma("unroll")                                                     \
    for (int j = 0; j < 4; ++j)                                           \
        _Pragma("unroll")                                                 \
        for (int bb = 0; bb < 8; ++bb)                                    \
            acc[j][bb] += wv[j] * av[bb]; }

// ---------------- persistent sequential loop -------------------------------
// 160 blocks x 512 threads, point-to-point flag sync (R3/R6 scheme).
// PB blocks keep M in LDS (aliased over unused Wt); r via shuffle-reduce.
__global__ __launch_bounds__(512)
void ntm_loop(const float* __restrict__ Wih, const float* __restrict__ Whh,
              const float* __restrict__ bl,  const float* __restrict__ bhead,
              float* __restrict__ ws)
{
    float* xT  = ws + OFF_XT;
    float* hA  = ws + OFF_HA;
    float* rA  = ws + OFF_RA;
    unsigned* bar = (unsigned*)(ws + OFF_BAR);
    unsigned* flag_h = bar;            // [128] stride 16
    unsigned* flag_r = bar + 4096;     // [32]  stride 16
    const unsigned short* whH = (const unsigned short*)(ws + OFF_WHH);

    __shared__ float Wt[K_ * 18];     // gate blocks: weights; PB: M storage
    __shared__ float p_lds[P_];
    __shared__ float wldsR[128];
    __shared__ float wldsW[128];
    __shared__ float h_lds[H_];       // PB: h staging; aliased scratch later
    __shared__ unsigned syncf[4];     // LDS flag mirrors

    const int tid  = threadIdx.x;
    const int bi   = blockIdx.x;
    const bool isPB = (bi < NPB);
    const int gi   = bi - NPB;        // gate block index 0..127

    if (tid < 4) syncf[tid] = 0;

    float* Mlds = Wt;                 // PB alias: M[128][MST] = 34.8 KB

    if (!isPB) {
        for (int idx = tid; idx < K_ * 16; idx += 512) {
            int rl = idx & 15, k = idx >> 4;
            int row = (rl & 3) * H_ + gi * 4 + (rl >> 2);
            float v = (k < I_ + C_) ? Wih[row * (I_ + C_) + k]
                                    : Whh[row * H_ + (k - (I_ + C_))];
            Wt[k * 18 + rl] = v;
        }
    } else {
        if (tid < N_) {
            wldsR[tid] = (tid == 0) ? 1.f : 0.f;
            wldsW[tid] = (tid == 0) ? 1.f : 0.f;
        }
        for (int idx = tid; idx < (N_ * C_) / 4; idx += 512) {
            const int n = idx >> 4;
            const int c = (idx & 15) << 2;
            float4 m4 = {0.01f, 0.01f, 0.01f, 0.01f};
            *(float4*)&Mlds[n * MST + c] = m4;
        }
    }
    __syncthreads();   // staging + syncf visible

    const int pair = tid >> 5;        // 0..15
    const int ks   = tid & 31;        // split-K lane
    const int rg   = pair >> 2;       // unit_local 0..3
    const int bg   = pair & 3;        // batch octet 0..3
    const int b0   = bg * 8;          // 8 batches per pair

    float acc[4][8];
    float cr[8] = {0,0,0,0,0,0,0,0};  // LSTM c (ks==0 lanes)
    float bI = 0, bF = 0, bG = 0, bO = 0;
    if (!isPB && ks == 0) {
        const int unit = gi * 4 + rg;
        bI = bl[unit];        bF = bl[H_ + unit];
        bG = bl[2*H_ + unit]; bO = bl[3*H_ + unit];
    }

    if (!isPB) {
        // pre-loop partial(0): x[0] + h[0](=0)
        #pragma unroll
        for (int j = 0; j < 4; ++j)
            #pragma unroll
            for (int bb = 0; bb < 8; ++bb) acc[j][bb] = 0.f;
        const float* xs = xT;
        const float* hs = hA;
        #pragma unroll
        for (int i = 0; i < 8; ++i) {
            const int k = ks + (i << 5);
            GEMM_STEP(k, xs + k * B_ + b0);
        }
        #pragma unroll
        for (int i = 0; i < 16; ++i) {
            const int k = ks + (i << 5);
            GEMM_STEP(320 + k, hs + k * B_ + b0);
        }

        // ================= gate block main loop =================
        for (int t = 0; t < S_; ++t) {
            // wait r[t] (32 PB flags); t=0 trivially satisfied
            wait_flags(flag_r, NPB, (unsigned)t, &syncf[0], tid);

            const float* rs = rA + (size_t)t * C_ * B_;
            #pragma unroll
            for (int i = 0; i < 2; ++i) {
                const int k = ks + (i << 5);
                GEMM_STEP(256 + k, rs + k * B_ + b0);
            }
            #pragma unroll
            for (int j = 0; j < 4; ++j)
                #pragma unroll
                for (int bb = 0; bb < 8; ++bb) {
                    float v = acc[j][bb];
                    v += __shfl_xor(v, 16, 64);
                    v += __shfl_xor(v, 8, 64);
                    v += __shfl_xor(v, 4, 64);
                    v += __shfl_xor(v, 2, 64);
                    v += __shfl_xor(v, 1, 64);
                    acc[j][bb] = v;
                }
            if (ks == 0) {
                const int unit = gi * 4 + rg;
                float hv[8];
                #pragma unroll
                for (int bb = 0; bb < 8; ++bb) {
                    float gI = acc[0][bb] + bI;
                    float gF = acc[1][bb] + bF;
                    float gG = acc[2][bb] + bG;
                    float gO = acc[3][bb] + bO;
                    float cN = sigm(gF) * cr[bb] + sigm(gI) * tanhf(gG);
                    hv[bb] = sigm(gO) * tanhf(cN);
                    cr[bb] = cN;
                }
                // publish as 4x 64-bit agent stores
                float* dst = &hA[(size_t)(t + 1) * HB + unit * B_ + b0];
                #pragma unroll
                for (int q = 0; q < 4; ++q) {
                    union { float f[2]; unsigned long long u; } pk;
                    pk.f[0] = hv[2 * q]; pk.f[1] = hv[2 * q + 1];
                    __hip_atomic_store((unsigned long long*)(dst + 2 * q), pk.u,
                                       __ATOMIC_RELAXED, __HIP_MEMORY_SCOPE_AGENT);
                }
            }
            __syncthreads();           // drains every lane's h stores
            if (tid == 0) {
                asm volatile("s_waitcnt vmcnt(0) lgkmcnt(0)" ::: "memory");
                __hip_atomic_store(&flag_h[gi * 16], (unsigned)(t + 1),
                                   __ATOMIC_RELAXED, __HIP_MEMORY_SCOPE_AGENT);
            }
            // wait full h[t+1] (128 gate flags), then next partial
            wait_flags(flag_h, NGATE, (unsigned)(t + 1), &syncf[2], tid);

            #pragma unroll
            for (int j = 0; j < 4; ++j)
                #pragma unroll
                for (int bb = 0; bb < 8; ++bb) acc[j][bb] = 0.f;
            if (t + 1 < S_) {
                const float* xs2 = xT + (size_t)(t + 1) * I_ * B_;
                const float* hs2 = hA + (size_t)(t + 1) * HB;
                #pragma unroll
                for (int i = 0; i < 8; ++i) {
                    const int k = ks + (i << 5);
                    GEMM_STEP(k, xs2 + k * B_ + b0);
                }
                #pragma unroll
                for (int i = 0; i < 16; ++i) {
                    const int k = ks + (i << 5);
                    GEMM_STEP(320 + k, hs2 + k * B_ + b0);
                }
            }
        }
        return;
    }

    // ================= PB block main loop =================
    const int b = bi;
    for (int t = 0; t < S_; ++t) {
        wait_flags(flag_h, NGATE, (unsigned)(t + 1), &syncf[0], tid);

        const float* hs = hA + (size_t)(t + 1) * HB;
        h_lds[tid] = __hip_atomic_load(&hs[tid * B_ + b], __ATOMIC_RELAXED,
                                       __HIP_MEMORY_SCOPE_AGENT);
        __syncthreads();

        // head GEMM (fp16 weights): p = W_head @ h + b_head, 2 thr/row
        {
            const int sub  = tid & 1;
            const int row0 = tid >> 1;
            const float* hb = &h_lds[sub * 256];
            #pragma unroll
            for (int rep = 0; rep < 2; ++rep) {
                const int row = (rep == 0) ? row0
                              : ((row0 < P_ - 256) ? row0 + 256 : -1);
                if (row >= 0) {
                    const unsigned short* wrow = whH + row * H_ + sub * 256;
                    float acch = 0.f;
                    #pragma unroll 4
                    for (int k2 = 0; k2 < 256; k2 += 8) {
                        float4 raw = *(const float4*)&wrow[k2];
                        const __half2* hp = (const __half2*)&raw;
                        float2 f0 = __half22float2(hp[0]);
                        float2 f1 = __half22float2(hp[1]);
                        float2 f2 = __half22float2(hp[2]);
                        float2 f3 = __half22float2(hp[3]);
                        acch += f0.x * hb[k2]     + f0.y * hb[k2 + 1]
                              + f1.x * hb[k2 + 2] + f1.y * hb[k2 + 3]
                              + f2.x * hb[k2 + 4] + f2.y * hb[k2 + 5]
                              + f3.x * hb[k2 + 6] + f3.y * hb[k2 + 7];
                    }
                    acch += __shfl_xor(acch, 1, 64);
                    if (sub == 0) p_lds[row] = acch + bhead[row];
                }
            }
        }
        __syncthreads();

        // dual-pass addressing: grp0=read head, grp1=write head (concurrent)
        {
            float* wtmpA = h_lds;            // alias (h_lds dead)
            float* sbufA = h_lds + 256;
            const int grp = (tid >> 7) & 1;
            const int l   = tid & 127;
            const bool act256 = (tid < 256);
            const int o = grp ? 70 : 0;
            const int widx = (tid >> 6) & 1;

            float z = 0.f, gate = 0.f, s0 = 0.f, s1 = 0.f, s2 = 0.f,
                  gamma = 1.f;
            if (act256) {
                float beta = splus(p_lds[o + 64]);
                gate = sigm(p_lds[o + 65]);
                float sa = p_lds[o + 66], sbv = p_lds[o + 67],
                      sc = p_lds[o + 68];
                float sm3 = fmaxf(sa, fmaxf(sbv, sc));
                float ea = __expf(sa - sm3), eb = __expf(sbv - sm3),
                      ec = __expf(sc - sm3);
                float es3 = ea + eb + ec;
                s0 = ea / es3; s1 = eb / es3; s2 = ec / es3;
                gamma = 1.f + splus(p_lds[o + 69]);
                float kk = 0.f;
                #pragma unroll 8
                for (int c = 0; c < C_; ++c) {
                    float kv = p_lds[o + c]; kk += kv * kv;
                }
                const float knorm = sqrtf(kk) + EPSX;
                float dot = 0.f, mm = 0.f;
                #pragma unroll
                for (int c = 0; c < C_; c += 4) {
                    float4 m4 = *(const float4*)&Mlds[l * MST + c];
                    dot += m4.x * p_lds[o + c]     + m4.y * p_lds[o + c + 1]
                         + m4.z * p_lds[o + c + 2] + m4.w * p_lds[o + c + 3];
                    mm  += m4.x * m4.x + m4.y * m4.y + m4.z * m4.z
                         + m4.w * m4.w;
                }
                z = beta * (dot / ((sqrtf(mm) + EPSX) * knorm));
            }
            float zm = wave_max(z);
            if (act256 && (tid & 63) == 0) sbufA[grp * 8 + widx] = zm;
            __syncthreads();
            const float zmax = fmaxf(sbufA[grp * 8], sbufA[grp * 8 + 1]);
            float ev = act256 ? __expf(z - zmax) : 0.f;
            float es = wave_sum(ev);
            if (act256 && (tid & 63) == 0) sbufA[grp * 8 + 2 + widx] = es;
            __syncthreads();
            const float esum = sbufA[grp * 8 + 2] + sbufA[grp * 8 + 3];
            if (act256) {
                float wc = ev / esum;
                float wprev = grp ? wldsW[l] : wldsR[l];
                wtmpA[grp * 128 + l] = gate * wc + (1.f - gate) * wprev;
            }
            __syncthreads();
            float wp = 0.f;
            if (act256) {
                float wsft = s0 * wtmpA[grp * 128 + ((l + 1) & 127)]
                           + s1 * wtmpA[grp * 128 + l]
                           + s2 * wtmpA[grp * 128 + ((l - 1) & 127)];
                wp = __powf(wsft + EPSX, gamma);
            }
            float ps = wave_sum(wp);
            if (act256 && (tid & 63) == 0) sbufA[grp * 8 + 4 + widx] = ps;
            __syncthreads();
            const float psum = sbufA[grp * 8 + 4] + sbufA[grp * 8 + 5];
            if (act256) {
                float wn = wp / psum;
                if (grp) wldsW[l] = wn; else wldsR[l] = wn;
            }
            __syncthreads();
        }

        // M = M*(1 - w_w e) + w_w a   (in LDS, no atomics)
        for (int idx = tid; idx < (N_ * C_) / 4; idx += 512) {
            const int n = idx >> 4;
            const int c = (idx & 15) << 2;
            const float wwn = wldsW[n];
            float4 m4 = *(float4*)&Mlds[n * MST + c];
            m4.x = m4.x * (1.f - wwn * sigm(p_lds[140 + c]))     + wwn * p_lds[204 + c];
            m4.y = m4.y * (1.f - wwn * sigm(p_lds[140 + c + 1])) + wwn * p_lds[204 + c + 1];
            m4.z = m4.z * (1.f - wwn * sigm(p_lds[140 + c + 2])) + wwn * p_lds[204 + c + 2];
            m4.w = m4.w * (1.f - wwn * sigm(p_lds[140 + c + 3])) + wwn * p_lds[204 + c + 3];
            *(float4*)&Mlds[n * MST + c] = m4;
        }
        __syncthreads();

        // r = w_r @ M_new (LDS reads, shuffle reduce) -> publish
        {
            const int c = tid >> 3, ns = tid & 7;
            float accr = 0.f;
            #pragma unroll
            for (int i = 0; i < 16; ++i) {
                const int n = ns + 8 * i;
                accr += wldsR[n] * Mlds[n * MST + c];
            }
            accr += __shfl_xor(accr, 4, 64);
            accr += __shfl_xor(accr, 2, 64);
            accr += __shfl_xor(accr, 1, 64);
            if (ns == 0)
                __hip_atomic_store(&rA[(size_t)(t + 1) * C_ * B_ + c * B_ + b],
                                   accr, __ATOMIC_RELAXED,
                                   __HIP_MEMORY_SCOPE_AGENT);
        }
        __syncthreads();               // drain r stores
        if (tid == 0) {
            asm volatile("s_waitcnt vmcnt(0) lgkmcnt(0)" ::: "memory");
            __hip_atomic_store(&flag_r[b * 16], (unsigned)(t + 1),
                               __ATOMIC_RELAXED, __HIP_MEMORY_SCOPE_AGENT);
        }
    }
}

// ---------------- final output GEMM ----------------
__global__ __launch_bounds__(256)
void out_kernel(const float* __restrict__ ws, const float* __restrict__ bout,
                float* __restrict__ out)
{
    __shared__ float actL[(H_ + C_) * 16];
    const float* hA  = ws + OFF_HA;
    const float* rA  = ws + OFF_RA;
    const float* WoT = ws + OFF_WOT;
    const int t   = blockIdx.x >> 1;
    const int bh  = blockIdx.x & 1;
    const int tid = threadIdx.x;

    for (int idx = tid; idx < (H_ + C_) * 16; idx += 256) {
        const int k = idx >> 4, bl2 = idx & 15, b = bh * 16 + bl2;
        float v = (k < H_) ? hA[(size_t)(t + 1) * HB + k * B_ + b]
                           : rA[(size_t)(t + 1) * C_ * B_ + (k - H_) * B_ + b];
        actL[k * 16 + bl2] = v;
    }
    __syncthreads();

    const int ot = tid & 63, bt = tid >> 6;
    const int o0 = ot * 4, bl0 = bt * 4;
    float acc[4][4] = {{0,0,0,0},{0,0,0,0},{0,0,0,0},{0,0,0,0}};
    for (int k = 0; k < H_ + C_; ++k) {
        const float4 w4 = *(const float4*)&WoT[k * O_ + o0];
        const float4 a4 = *(const float4*)&actL[k * 16 + bl0];
        const float wv[4] = {w4.x, w4.y, w4.z, w4.w};
        const float av[4] = {a4.x, a4.y, a4.z, a4.w};
        #pragma unroll
        for (int j = 0; j < 4; ++j)
            #pragma unroll
            for (int bb = 0; bb < 4; ++bb)
                acc[j][bb] += wv[j] * av[bb];
    }
    const float4 bo = *(const float4*)&bout[o0];
    #pragma unroll
    for (int bb = 0; bb < 4; ++bb) {
        const int b = bh * 16 + bl0 + bb;
        float4 res;
        res.x = acc[0][bb] + bo.x;
        res.y = acc[1][bb] + bo.y;
        res.z = acc[2][bb] + bo.z;
        res.w = acc[3][bb] + bo.w;
        *(float4*)&out[((size_t)b * S_ + t) * O_ + o0] = res;
    }
}

extern "C" void kernel_launch(void* const* d_in, const int* in_sizes, int n_in,
                              void* d_out, int out_size, void* d_ws, size_t ws_size,
                              hipStream_t stream)
{
    const float* x    = (const float*)d_in[0];
    const float* Wih  = (const float*)d_in[1];
    const float* Whh  = (const float*)d_in[2];
    const float* bl   = (const float*)d_in[3];
    const float* bhd  = (const float*)d_in[4];
    const float* Wout = (const float*)d_in[6];
    const float* bout = (const float*)d_in[7];
    const float* Whd  = (const float*)d_in[4];
    const float* bhead2 = (const float*)d_in[5];
    float* ws  = (float*)d_ws;
    float* out = (float*)d_out;

    prep_kernel<<<10529, 256, 0, stream>>>(x, Wout, Whd, ws);

    void* args[] = { (void*)&Wih, (void*)&Whh, (void*)&bl,
                     (void*)&bhead2, (void*)&ws };
    (void)hipLaunchCooperativeKernel((void*)ntm_loop, dim3(NBLK), dim3(512), args, 0, stream);

    out_kernel<<<512, 256, 0, stream>>>(ws, bout, out);
}